// Round 1
// baseline (216.081 us; speedup 1.0000x reference)
//
#include <hip/hip_runtime.h>

// Problem: B=32, H=W=128, C_IN=C_OUT=32, 3x3 SAME conv with per-sample
// hypernetwork weights Wk[b] = (P[b] @ dense_w).reshape(3,3,32,32).
//
// Implicit-GEMM formulation per image b:
//   Y[p, co] = sum_k Xpatch[p, k] * W[k, co],  p = h*128+w (M=16384), N=32, K=288
// K-order is (kh, kw, ci) with ci innermost => K-chunk kc (32 wide) == tap
// (kh,kw) = (kc/3, kc%3), chunk-local k == ci. So the 16x16x32 f16 MFMA
// A-fragment (A[m=lane&15][k=(lane>>4)*8+j], HW-verified layout) is 8
// consecutive ci of one pixel: two float4 loads from X, coalesced.

#define BATCH 32
#define HDIM 128
#define WDIM 128
#define CIN 32
#define COUT 32
#define PDIM 128
#define KCOLS 9216  // 3*3*32*32

typedef _Float16 f16x8 __attribute__((ext_vector_type(8)));
typedef float f32x4 __attribute__((ext_vector_type(4)));

// ---------------------------------------------------------------------------
// Kernel A: A = P @ dense_w  (32x128 @ 128x9216), output converted to f16 and
// swizzled into MFMA B-fragment layout:
//   WB[b][kc][ct][lane][j8], lane = quad*16 + (co&15), quad = (ci&31)>>3,
//   j8 = ci&7, ct = co>>4.  B-frag lane l holds W[kc*32 + (l>>4)*8 + j][ct*16 + (l&15)].
// ---------------------------------------------------------------------------
__global__ __launch_bounds__(256) void hyper_gemm(const float* __restrict__ P,
                                                  const float* __restrict__ Dw,
                                                  unsigned short* __restrict__ WB) {
    const int col = blockIdx.x * 256 + threadIdx.x;  // 0..9215
    float acc[BATCH];
#pragma unroll
    for (int b = 0; b < BATCH; ++b) acc[b] = 0.f;

    for (int m = 0; m < PDIM; ++m) {
        float dw = Dw[m * KCOLS + col];  // coalesced across threads
#pragma unroll
        for (int b = 0; b < BATCH; ++b) {
            acc[b] += P[b * PDIM + m] * dw;  // uniform index -> s_load
        }
    }

    // col = ((kh*3+kw)*32 + ci)*32 + co
    const int k = col >> 5;        // (kh*3+kw)*32 + ci
    const int co = col & 31;
    const int kc = k >> 5;         // tap index 0..8
    const int kr = k & 31;         // == ci
    const int quad = kr >> 3;
    const int j8 = kr & 7;
    const int ct = co >> 4;
    const int lane = quad * 16 + (co & 15);
    const int base = (((kc * 2 + ct) * 64 + lane) * 8 + j8);  // within one b (4608 elems? no: 9*2*512=9216)
#pragma unroll
    for (int b = 0; b < BATCH; ++b) {
        _Float16 v = (_Float16)acc[b];
        WB[b * KCOLS + base] = __builtin_bit_cast(unsigned short, v);
    }
}

// ---------------------------------------------------------------------------
// Kernel B: per-image implicit-GEMM conv with f16 MFMA.
// Grid: 32 b * 32 row-groups = 1024 blocks, 256 thr = 4 waves.
// Wave v owns row h = hg*4 + v; loops 8 tiles of 16 pixels (w).
// 18 B-fragments (9 taps x 2 co-halves) live in registers for the whole block.
// ---------------------------------------------------------------------------
__global__ __launch_bounds__(256) void cond_conv(const float* __restrict__ X,
                                                 const unsigned short* __restrict__ WB,
                                                 float* __restrict__ Y) {
    const int b = blockIdx.x >> 5;
    const int hg = blockIdx.x & 31;
    const int wave = threadIdx.x >> 6;
    const int lane = threadIdx.x & 63;
    const int h = hg * 4 + wave;
    const int quad = lane >> 4;
    const int m16 = lane & 15;

    // Load the 18 B-fragments: 16B contiguous per lane, 1KB per wave. In regs.
    f16x8 bfrag[9][2];
#pragma unroll
    for (int kc = 0; kc < 9; ++kc) {
#pragma unroll
        for (int ct = 0; ct < 2; ++ct) {
            const f16x8* p = (const f16x8*)(WB + (size_t)b * KCOLS +
                                            (((kc * 2 + ct) * 64 + lane) * 8));
            bfrag[kc][ct] = *p;
        }
    }

    const f32x4* X4 = (const f32x4*)X;

    for (int w0 = 0; w0 < WDIM; w0 += 16) {
        f32x4 acc0 = {0.f, 0.f, 0.f, 0.f};
        f32x4 acc1 = {0.f, 0.f, 0.f, 0.f};
#pragma unroll
        for (int kc = 0; kc < 9; ++kc) {
            const int kh = kc / 3, kw = kc % 3;
            const int hh = h + kh - 1;               // wave-uniform
            const int ww = w0 + m16 + kw - 1;        // per-lane
            const bool ok = (hh >= 0) & (hh < HDIM) & (ww >= 0) & (ww < WDIM);
            int idx = ((b * HDIM + hh) * WDIM + ww) * 8 + quad * 2;  // float4 units
            idx = ok ? idx : 0;
            f32x4 lo = X4[idx];
            f32x4 hi = X4[idx + 1];
            if (!ok) { lo = (f32x4)(0.f); hi = (f32x4)(0.f); }
            f16x8 a;
#pragma unroll
            for (int j = 0; j < 4; ++j) {
                a[j] = (_Float16)lo[j];
                a[4 + j] = (_Float16)hi[j];
            }
            acc0 = __builtin_amdgcn_mfma_f32_16x16x32_f16(a, bfrag[kc][0], acc0, 0, 0, 0);
            acc1 = __builtin_amdgcn_mfma_f32_16x16x32_f16(a, bfrag[kc][1], acc1, 0, 0, 0);
        }
        // D layout: D[row][col], col = lane&15 (co within half), row = quad*4+r (pixel)
        float* yp = Y + (((size_t)(b * HDIM + h) * WDIM) + w0 + quad * 4) * COUT + m16;
#pragma unroll
        for (int r = 0; r < 4; ++r) {
            yp[r * COUT] = acc0[r];
            yp[r * COUT + 16] = acc1[r];
        }
    }
}

extern "C" void kernel_launch(void* const* d_in, const int* in_sizes, int n_in,
                              void* d_out, int out_size, void* d_ws, size_t ws_size,
                              hipStream_t stream) {
    const float* X = (const float*)d_in[0];   // [32,128,128,32]
    const float* P = (const float*)d_in[1];   // [32,128]
    const float* Dw = (const float*)d_in[2];  // [128,9216]
    float* Y = (float*)d_out;                 // [32,128,128,32]
    unsigned short* WB = (unsigned short*)d_ws;  // 32*9216 f16 = 576 KiB

    hipLaunchKernelGGL(hyper_gemm, dim3(KCOLS / 256), dim3(256), 0, stream, P, Dw, WB);
    hipLaunchKernelGGL(cond_conv, dim3(BATCH * 32), dim3(256), 0, stream, X, WB, Y);
}